// Round 4
// baseline (318.393 us; speedup 1.0000x reference)
//
#include <hip/hip_runtime.h>

// SSIM loss v4 — streaming separable conv with global_load_lds DMA pipeline.
// Grid 4 x 16 x 48, block = 128 threads = 2 independent waves (no barriers).
// Wave strip: 64 cols x 32 rows (42 input rows incl halo). Each lane owns one
// output column.
// LDS: per-wave ring of 4 row-slots; slot = [A row: 80 floats][B row: 80].
// Pipeline: DMA (global_load_lds, 16B x 20 lanes per image) fills slot s+3
// while step s computes; manual s_waitcnt vmcnt(4) guarantees slot s landed
// while keeping slots s+1,s+2 in flight (never drains to 0).
// Edge rows/cols: per-lane address select to a zeroed 16B region of d_ws ->
// uniform 2 DMAs/step (exact vmcnt accounting) + free zero padding.
// Clamp (nan_to_num+clip) applied at window read (pk max/min).
// Horizontal 11-tap -> 12-slot register ring -> vertical 11-tap + SSIM map,
// wave reduce, one atomicAdd; finalize kernel: 1 - sum/N.

typedef float v2f __attribute__((ext_vector_type(2)));

#define IMG    512
#define SROWS  32
#define NSTEPS 42            // SROWS + 10
#define NPIX   (16.0f * 3.0f * 512.0f * 512.0f)

// s_waitcnt simm16 (gfx9): vmcnt[3:0]=b3:0, exp=b6:4, lgkm=b11:8, vmcnt[5:4]=b15:14
#define WAITCNT_VM4 0x0F74   // vmcnt(4), exp/lgkm unconstrained

__device__ __forceinline__ void dma16(const float* g, float* l) {
    __builtin_amdgcn_global_load_lds(
        (const __attribute__((address_space(1))) void*)g,
        (__attribute__((address_space(3))) void*)l, 16, 0, 0);
}

__device__ __forceinline__ float ssim_px(v2f mu, v2f e, float e12) {
    const float C1 = 1.01e-4f;   // 0.01^2 + 1e-6
    const float C2 = 9.01e-4f;   // 0.03^2 + 1e-6
    v2f musq = mu * mu;
    float mu12 = mu.x * mu.y;
    v2f sig = e - musq;
    v2f lo = {1e-6f, 1e-6f};
    v2f hi = {1e6f, 1e6f};
    sig = __builtin_elementwise_max(sig, lo);
    sig = __builtin_elementwise_min(sig, hi);
    float s12 = e12 - mu12;
    float num = fmaf(2.f, mu12, C1) * fmaf(2.f, s12, C2);
    float den = (musq.x + musq.y + C1) * (sig.x + sig.y + C2);  // >= C1*C2 > 0
    return num * __builtin_amdgcn_rcpf(den);
}

__global__ __launch_bounds__(128, 4)
void ssim_dma_kernel(const float* __restrict__ imgA,
                     const float* __restrict__ imgB,
                     const float* __restrict__ zeroSrc,  // >=16B of zeros
                     float* __restrict__ accum)
{
    constexpr float GW[11] = {
        0.00102838f, 0.00759880f, 0.03600077f, 0.10936070f, 0.21300554f,
        0.26601173f,
        0.21300554f, 0.10936070f, 0.03600077f, 0.00759880f, 0.00102838f
    };

    __shared__ __attribute__((aligned(16))) float sbuf[2][4][160];

    const int tid  = threadIdx.x;
    const int wv   = tid >> 6;
    const int lane = tid & 63;
    float (*slots)[160] = sbuf[wv];

    const int C0 = blockIdx.x * 128 + wv * 64;
    const int R0 = blockIdx.y * SROWS;
    const size_t pOff = (size_t)blockIdx.z * (size_t)(IMG * IMG);

    // staging lanes: 20 lanes x 16B per image per row
    const bool stg  = lane < 20;
    const int col0  = C0 - 8 + 4 * lane;
    const bool okc  = stg && (col0 >= 0) && (col0 <= IMG - 4);
    const float* aCol = imgA + pOff + col0;
    const float* bCol = imgB + pOff + col0;

    auto issue = [&](int s, int slot) {
        if (stg) {
            const int ir = R0 - 5 + s;
            const bool ok = okc && ((unsigned)ir < (unsigned)IMG);
            const size_t ro = (size_t)ir * IMG;
            const float* ga = ok ? (aCol + ro) : zeroSrc;
            const float* gb = ok ? (bCol + ro) : zeroSrc;
            dma16(ga, &slots[slot][0]);
            dma16(gb, &slots[slot][80]);
        }
    };

    // 12-slot register ring of horizontal results
    v2f rA[12], rB[12];
    float rC[12];
#pragma unroll
    for (int i = 0; i < 12; ++i) { rA[i] = 0; rB[i] = 0; rC[i] = 0; }

    float lsum = 0.f;

    auto body = [&](int s, int u, bool dovert) {
        // slot s's two DMAs are the oldest pending of 6 -> vmcnt(4)
        __builtin_amdgcn_s_waitcnt(WAITCNT_VM4);

        // window read + clamp: cols X-5..X+5, X = C0+lane
        const float* sa = &slots[u & 3][lane + 3];
        v2f w[11];
#pragma unroll
        for (int j = 0; j < 11; ++j) {
            float a = sa[j];        // A row, word lane+3+j
            float b = sa[80 + j];   // B row (same base -> ds_read2_b32 pair)
            v2f t = {a, b};
            t = __builtin_elementwise_max(t, (v2f){0.f, 0.f});
            t = __builtin_elementwise_min(t, (v2f){1.f, 1.f});
            w[j] = t;
        }

        // refill the pipeline: slot s+3 (disjoint from slot s%4)
        issue(s + 3, (u + 3) & 3);

        // horizontal 11-tap (packed f32)
        v2f hA = 0, hB = 0;
        float hC = 0;
#pragma unroll
        for (int j = 0; j < 11; ++j) {
            v2f wj = w[j];
            v2f g  = GW[j] * wj;            // {g*a, g*b}
            hA += g;                        // {h1, h2}
            hB += g * wj;                   // {h11, h22}
            hC  = fmaf(g.x, wj.y, hC);      // h12
        }
        rA[u] = hA; rB[u] = hB; rC[u] = hC;

        // vertical 11-tap from ring + SSIM (output row R0+s-10)
        if (dovert) {
            v2f vA = 0, vB = 0;
            float vC = 0;
#pragma unroll
            for (int i = 0; i < 11; ++i) {
                const int sl = (u + 2 + i) % 12;   // slot of step s-10+i
                const float gi = GW[i];
                vA += gi * rA[sl];
                vB += gi * rB[sl];
                vC  = fmaf(gi, rC[sl], vC);
            }
            lsum += ssim_px(vA, vB, vC);
        }
    };

    // prologue: fill slots 0..2 (6 DMAs in flight)
    issue(0, 0);
    issue(1, 1);
    issue(2, 2);

    // 3 chunks of 12 (s = 0..35), then static tail (s = 36..41).
    // chunk length 12 keeps both ring index (mod 12) and LDS slot (mod 4)
    // compile-time constant.
#pragma unroll 1
    for (int ch = 0; ch < 36; ch += 12) {
#pragma unroll
        for (int u = 0; u < 12; ++u)
            body(ch + u, u, (ch + u) >= 10);
    }
#pragma unroll
    for (int u = 0; u < 6; ++u)
        body(36 + u, u, true);

    // wave64 reduce, one atomic per wave
#pragma unroll
    for (int off = 32; off >= 1; off >>= 1)
        lsum += __shfl_down(lsum, off, 64);
    if (lane == 0) atomicAdd(accum, lsum);
}

__global__ void ssim_finalize_kernel(const float* __restrict__ accum,
                                     float* __restrict__ out) {
    out[0] = 1.0f - accum[0] * (1.0f / NPIX);
}

extern "C" void kernel_launch(void* const* d_in, const int* in_sizes, int n_in,
                              void* d_out, int out_size, void* d_ws, size_t ws_size,
                              hipStream_t stream) {
    const float* img1 = (const float*)d_in[0];
    const float* img2 = (const float*)d_in[1];
    float* out = (float*)d_out;
    float* wsf = (float*)d_ws;

    // ws[0] = accumulator, ws[16..] = zero source for edge DMAs
    hipMemsetAsync(wsf, 0, 256, stream);

    dim3 grid(4, 16, 48);   // 3072 blocks x 2 waves = 6144 waves
    ssim_dma_kernel<<<grid, 128, 0, stream>>>(img1, img2, wsf + 16, wsf);
    ssim_finalize_kernel<<<1, 1, 0, stream>>>(wsf, out);
}